// Round 5
// baseline (172.898 us; speedup 1.0000x reference)
//
#include <hip/hip_runtime.h>
#include <hip/hip_bf16.h>

#define NF   1024   // N features
#define NHID 256    // H hidden
#define NJ   1280   // N+H keys
#define ED   64     // E = HD = 64
#define BATCH 8192
#define SCB  640    // score block threads (10 waves); SCB*2 = 1280 = NJ

#if defined(__has_builtin) && __has_builtin(__builtin_amdgcn_exp2f)
#define EXP2(x) __builtin_amdgcn_exp2f(x)
#else
#define EXP2(x) exp2f(x)
#endif
#define K2E 2.8853900817779268f   // 2*log2(e):  exp(2x) = exp2(K2E*x)

// ---- Kernel 1: A[i][e] = feat@W1 ; BvT[e][j] = (full@W2 + bw)^T ----
// 36 blocks: 16 A-blocks (64 rows) + 20 Bv-blocks (64 rows). Inputs staged via
// contiguous 16KB float4 copy (per-lane coalesced, no scalarization).
__global__ __launch_bounds__(256) void prep_kernel(
    const float* __restrict__ feat, const float* __restrict__ hid,
    const float* __restrict__ Ww, const float* __restrict__ bw,
    float* __restrict__ A, float* __restrict__ BvT)
{
    __shared__ __align__(16) float in_s[64][64];
    __shared__ __align__(16) float tout[64][65];
    const int tid = threadIdx.x;
    const int b   = blockIdx.x;
    const bool isA = (b < 16);
    const int e  = tid & 63;
    const int wv = tid >> 6;

    const float* W = isA ? Ww : (Ww + 4096);
    float wcol[64];
    #pragma unroll
    for (int k = 0; k < 64; k++) wcol[k] = W[k * 64 + e];   // coalesced, L2-hot
    const float bias = isA ? 0.f : bw[e];

    const int bb = isA ? b : (b - 16);
    const float* src = isA ? (feat + (size_t)bb * 4096)
                     : (bb < 16 ? (feat + (size_t)bb * 4096)
                                : (hid + (size_t)(bb - 16) * 4096));
    #pragma unroll
    for (int s = 0; s < 4; s++)
        ((float4*)&in_s[0][0])[tid + s * 256] = ((const float4*)src)[tid + s * 256];
    __syncthreads();

    float acc[16];
    #pragma unroll
    for (int r = 0; r < 16; r++) acc[r] = bias;
    for (int k4 = 0; k4 < 64; k4 += 4) {
        #pragma unroll
        for (int r = 0; r < 16; r++) {
            float4 iv = *(const float4*)&in_s[wv * 16 + r][k4];   // b128 broadcast
            acc[r] += iv.x*wcol[k4+0] + iv.y*wcol[k4+1] + iv.z*wcol[k4+2] + iv.w*wcol[k4+3];
        }
    }

    if (isA) {
        #pragma unroll
        for (int r = 0; r < 16; r++)
            A[(size_t)(b * 64 + wv * 16 + r) * 64 + e] = acc[r];
    } else {
        #pragma unroll
        for (int r = 0; r < 16; r++) tout[wv * 16 + r][e] = acc[r];
        __syncthreads();
        const int j0 = bb * 64;
        #pragma unroll
        for (int q = 0; q < 4; q++) {
            float4 v;
            v.x = tout[wv * 16 + q * 4 + 0][e];
            v.y = tout[wv * 16 + q * 4 + 1][e];
            v.z = tout[wv * 16 + q * 4 + 2][e];
            v.w = tout[wv * 16 + q * 4 + 3][e];
            *(float4*)&BvT[(size_t)e * NJ + j0 + wv * 16 + q * 4] = v;
        }
    }
}

// ---- Kernel 2: fused score / masked exp / rowsum / context.  I=4 rows/block ----
// 256 blocks x 640 threads. Lane owns 2 consecutive j (float2 BvT loads);
// 8 independent tanh chains/lane; BvT swept from L2 once per 4 rows.
__global__ __launch_bounds__(SCB) void score_ctx_kernel(
    const float* __restrict__ feat, const float* __restrict__ hid,
    const float* __restrict__ Wu, const float* __restrict__ A,
    const float* __restrict__ BvT, const void* __restrict__ maskp,
    float* __restrict__ ctx)
{
    __shared__ __align__(16) float4 sA4[64];          // A rows i0..i0+3 packed
    __shared__ __align__(16) float  sWu[64];
    __shared__ __align__(16) float  sc[4][NJ];        // 20 KB
    __shared__ __align__(16) float  red[4][40][64];   // 40 KB
    __shared__ float wpart[4][10];
    __shared__ float ssum[4];
    __shared__ float sSwu;
    __shared__ int   mtype_s;

    const int tid = threadIdx.x;
    const int i0  = blockIdx.x * 4;

    if (tid < 64) {
        const unsigned int* mw = (const unsigned int*)maskp;
        unsigned int w = mw[tid];
        unsigned long long notf = __ballot(w != 0u && w != 0x3F800000u);
        unsigned long long gt1  = __ballot(w > 1u);
        if (tid == 0) mtype_s = (notf == 0ull) ? 2 : ((gt1 == 0ull) ? 1 : 0);
        float wu = Wu[tid];
        float4 p;
        p.x = A[(size_t)(i0 + 0) * 64 + tid];
        p.y = A[(size_t)(i0 + 1) * 64 + tid];
        p.z = A[(size_t)(i0 + 2) * 64 + tid];
        p.w = A[(size_t)(i0 + 3) * 64 + tid];
        sA4[tid] = p;
        sWu[tid] = wu;
        float s = wu;
        #pragma unroll
        for (int off = 32; off > 0; off >>= 1) s += __shfl_down(s, off);
        if (tid == 0) sSwu = s;
    }
    __syncthreads();

    const int j2 = tid * 2;
    // acc[i].x/.y : row i, keys j2 / j2+1 :  sum_e wu*rcp(exp(2x)+1)
    float2 acc[4];
    #pragma unroll
    for (int i = 0; i < 4; i++) acc[i] = make_float2(0.f, 0.f);

    #pragma unroll 4
    for (int e = 0; e < 64; e++) {
        float2 b = *(const float2*)(BvT + (size_t)e * NJ + j2);
        float4 p = sA4[e];
        float wu = sWu[e];
        float x, r;
        x = p.x + b.x; r = __builtin_amdgcn_rcpf(EXP2(x*K2E) + 1.f); acc[0].x = fmaf(wu, r, acc[0].x);
        x = p.x + b.y; r = __builtin_amdgcn_rcpf(EXP2(x*K2E) + 1.f); acc[0].y = fmaf(wu, r, acc[0].y);
        x = p.y + b.x; r = __builtin_amdgcn_rcpf(EXP2(x*K2E) + 1.f); acc[1].x = fmaf(wu, r, acc[1].x);
        x = p.y + b.y; r = __builtin_amdgcn_rcpf(EXP2(x*K2E) + 1.f); acc[1].y = fmaf(wu, r, acc[1].y);
        x = p.z + b.x; r = __builtin_amdgcn_rcpf(EXP2(x*K2E) + 1.f); acc[2].x = fmaf(wu, r, acc[2].x);
        x = p.z + b.y; r = __builtin_amdgcn_rcpf(EXP2(x*K2E) + 1.f); acc[2].y = fmaf(wu, r, acc[2].y);
        x = p.w + b.x; r = __builtin_amdgcn_rcpf(EXP2(x*K2E) + 1.f); acc[3].x = fmaf(wu, r, acc[3].x);
        x = p.w + b.y; r = __builtin_amdgcn_rcpf(EXP2(x*K2E) + 1.f); acc[3].y = fmaf(wu, r, acc[3].y);
    }

    const float Swu = sSwu;
    const int mtype = mtype_s;
    const unsigned char* m8  = (const unsigned char*)maskp;
    const unsigned int*  m32 = (const unsigned int*)maskp;
    const float*         mfl = (const float*)maskp;

    float lsum[4];
    #pragma unroll
    for (int i = 0; i < 4; i++) {
        size_t off = (size_t)(i0 + i) * NJ + j2;
        bool b0, b1;
        if (mtype == 0) {
            unsigned short m = *(const unsigned short*)(m8 + off);
            b0 = (m & 0xffu) != 0; b1 = (m >> 8) != 0;
        } else if (mtype == 1) {
            uint2 m = *(const uint2*)(m32 + off);
            b0 = m.x != 0u; b1 = m.y != 0u;
        } else {
            float2 m = *(const float2*)(mfl + off);
            b0 = m.x != 0.f; b1 = m.y != 0.f;
        }
        float e0 = b0 ? __expf(Swu - 2.f * acc[i].x) : 0.f;
        float e1 = b1 ? __expf(Swu - 2.f * acc[i].y) : 0.f;
        *(float2*)&sc[i][j2] = make_float2(e0, e1);
        lsum[i] = e0 + e1;
    }
    #pragma unroll
    for (int off = 32; off > 0; off >>= 1) {
        lsum[0] += __shfl_down(lsum[0], off);
        lsum[1] += __shfl_down(lsum[1], off);
        lsum[2] += __shfl_down(lsum[2], off);
        lsum[3] += __shfl_down(lsum[3], off);
    }
    if ((tid & 63) == 0) {
        int wv = tid >> 6;
        wpart[0][wv] = lsum[0]; wpart[1][wv] = lsum[1];
        wpart[2][wv] = lsum[2]; wpart[3][wv] = lsum[3];
    }
    __syncthreads();
    if (tid < 4) {
        float s = 0.f;
        #pragma unroll
        for (int g = 0; g < 10; g++) s += wpart[tid][g];
        ssum[tid] = (s == 0.f) ? 1.f : s;
    }
    __syncthreads();

    // ---- phase 2: ctx[i][e] = (1/ssum_i) * sum_j sc[i][j] * full[j][e] ----
    const int jg = tid >> 4;             // 0..39
    const int e4 = (tid & 15) * 4;
    float4 c[4];
    #pragma unroll
    for (int i = 0; i < 4; i++) c[i] = make_float4(0.f, 0.f, 0.f, 0.f);
    for (int it = 0; it < 32; it++) {
        int j = it * 40 + jg;
        const float* fr = (j < NF) ? (feat + (size_t)j * 64)
                                   : (hid  + (size_t)(j - NF) * 64);
        float4 f = *(const float4*)(fr + e4);
        #pragma unroll
        for (int i = 0; i < 4; i++) {
            float w = sc[i][j];
            c[i].x += w*f.x; c[i].y += w*f.y; c[i].z += w*f.z; c[i].w += w*f.w;
        }
    }
    #pragma unroll
    for (int i = 0; i < 4; i++) *(float4*)&red[i][jg][e4] = c[i];
    __syncthreads();
    if (tid < 256) {
        int half = tid >> 6, e = tid & 63;
        float v = 0.f;
        #pragma unroll
        for (int g = 0; g < 40; g++) v += red[half][g][e];
        ctx[(size_t)(i0 + half) * 64 + e] = v / ssum[half];
    }
}

// ---- Kernel 3: out = values(8192x1024) @ ctx(1024x64), 64x64 tile, 8-way k-split ----
__global__ __launch_bounds__(256) void out_mm_kernel(
    const float* __restrict__ values, const float* __restrict__ ctxp,
    float* __restrict__ dst, int atomic_mode)
{
    __shared__ __align__(16) float vsT[64 * 64];
    __shared__ __align__(16) float cs[64][64];
    const int tid = threadIdx.x;
    const int rt  = blockIdx.x >> 3;     // 128 row tiles
    const int kq  = blockIdx.x & 7;      // 8 K-slices of 128
    const int r0  = rt * 64;
    const int tr  = tid >> 4;
    const int tc4 = (tid & 15) * 4;

    float acc[4][4];
    #pragma unroll
    for (int a = 0; a < 4; a++)
        #pragma unroll
        for (int b = 0; b < 4; b++) acc[a][b] = 0.f;

    for (int ch = 0; ch < 2; ch++) {
        const int k0 = kq * 128 + ch * 64;
        __syncthreads();
        #pragma unroll
        for (int s = 0; s < 4; s++) {           // stage V transposed+swizzled
            int t   = tid + s * 256;
            int r   = t >> 4;
            int kk4 = (t & 15) * 4;
            float4 g = *(const float4*)&values[(size_t)(r0 + r) * NF + k0 + kk4];
            int p  = (((r >> 2) + (t & 15)) & 15) * 4 + (r & 3);
            vsT[(kk4 + 0) * 64 + p] = g.x;
            vsT[(kk4 + 1) * 64 + p] = g.y;
            vsT[(kk4 + 2) * 64 + p] = g.z;
            vsT[(kk4 + 3) * 64 + p] = g.w;
        }
        #pragma unroll
        for (int s = 0; s < 4; s++) {           // stage ctx tile
            int t  = tid + s * 256;
            int kk = t >> 4;
            int c4 = (t & 15) * 4;
            *(float4*)&cs[kk][c4] = *(const float4*)&ctxp[(size_t)(k0 + kk) * ED + c4];
        }
        __syncthreads();
        #pragma unroll 8
        for (int k = 0; k < 64; k++) {
            float4 av = *(const float4*)&vsT[k * 64 + (((tr + (k >> 2)) & 15) << 2)];
            float4 bv = *(const float4*)&cs[k][tc4];
            acc[0][0] += av.x*bv.x; acc[0][1] += av.x*bv.y; acc[0][2] += av.x*bv.z; acc[0][3] += av.x*bv.w;
            acc[1][0] += av.y*bv.x; acc[1][1] += av.y*bv.y; acc[1][2] += av.y*bv.z; acc[1][3] += av.y*bv.w;
            acc[2][0] += av.z*bv.x; acc[2][1] += av.z*bv.y; acc[2][2] += av.z*bv.z; acc[2][3] += av.z*bv.w;
            acc[3][0] += av.w*bv.x; acc[3][1] += av.w*bv.y; acc[3][2] += av.w*bv.z; acc[3][3] += av.w*bv.w;
        }
    }
    if (atomic_mode) {
        #pragma unroll
        for (int i2 = 0; i2 < 4; i2++) {
            int r = r0 + tr * 4 + i2;
            float* op = dst + (size_t)r * ED + tc4;
            unsafeAtomicAdd(op + 0, acc[i2][0]);
            unsafeAtomicAdd(op + 1, acc[i2][1]);
            unsafeAtomicAdd(op + 2, acc[i2][2]);
            unsafeAtomicAdd(op + 3, acc[i2][3]);
        }
    } else {
        #pragma unroll
        for (int i2 = 0; i2 < 4; i2++) {
            int r = r0 + tr * 4 + i2;
            float* op = dst + ((size_t)kq * BATCH + r) * ED + tc4;
            *(float4*)op = make_float4(acc[i2][0], acc[i2][1], acc[i2][2], acc[i2][3]);
        }
    }
}

// ---- Kernel 4: out = sum of 8 partials (float4) ----
__global__ __launch_bounds__(256) void reduce8_kernel(
    const float* __restrict__ part, float* __restrict__ out)
{
    const size_t S = (size_t)BATCH * ED / 4;
    size_t idx = (size_t)blockIdx.x * 256 + threadIdx.x;
    const float4* p = (const float4*)part;
    float4 r = {0.f, 0.f, 0.f, 0.f};
    #pragma unroll
    for (int q = 0; q < 8; q++) {
        float4 a = p[idx + (size_t)q * S];
        r.x += a.x; r.y += a.y; r.z += a.z; r.w += a.w;
    }
    ((float4*)out)[idx] = r;
}

extern "C" void kernel_launch(void* const* d_in, const int* in_sizes, int n_in,
                              void* d_out, int out_size, void* d_ws, size_t ws_size,
                              hipStream_t stream) {
    const float* values = (const float*)d_in[0];
    const float* feat   = (const float*)d_in[1];
    const float* hid    = (const float*)d_in[2];
    const float* Ww     = (const float*)d_in[3];
    const float* bw     = (const float*)d_in[4];
    const float* Wu     = (const float*)d_in[5];
    const void*  mask   = d_in[6];
    float* out = (float*)d_out;

    float* A    = (float*)d_ws;                        // 1024*64      = 256 KiB
    float* BvT  = A + (size_t)NF * 64;                 // 64*1280      = 320 KiB
    float* ctx  = BvT + (size_t)ED * NJ;               // 1024*64      = 256 KiB
    float* part = ctx + (size_t)NF * 64;               // 8*8192*64*4  = 16  MiB
    const size_t need = ((size_t)NF*64 + (size_t)ED*NJ + (size_t)NF*64
                         + (size_t)8*BATCH*ED) * sizeof(float);
    const bool wsmode = ws_size >= need;

    hipLaunchKernelGGL(prep_kernel, dim3(36), dim3(256), 0, stream,
                       feat, hid, Ww, bw, A, BvT);
    hipLaunchKernelGGL(score_ctx_kernel, dim3(NF / 4), dim3(SCB), 0, stream,
                       feat, hid, Wu, A, BvT, mask, ctx);
    if (wsmode) {
        hipLaunchKernelGGL(out_mm_kernel, dim3(1024), dim3(256), 0, stream,
                           values, ctx, part, 0);
        hipLaunchKernelGGL(reduce8_kernel, dim3(BATCH * ED / 4 / 256), dim3(256), 0, stream,
                           part, out);
    } else {
        hipMemsetAsync(d_out, 0, (size_t)BATCH * ED * sizeof(float), stream);
        hipLaunchKernelGGL(out_mm_kernel, dim3(1024), dim3(256), 0, stream,
                           values, ctx, out, 1);
    }
}